// Round 6
// baseline (365.829 us; speedup 1.0000x reference)
//
#include <hip/hip_runtime.h>
#include <hip/hip_bf16.h>

#define DD 768
#define NN 8192
#define TT 1024
#define FF 16
#define LL 8
#define CVV 512
#define TVV 512

typedef __attribute__((ext_vector_type(8))) short bf16x8;
typedef __attribute__((ext_vector_type(4))) float f32x4;

__device__ inline unsigned short f2bf(float f) {
    union { float f; unsigned u; } v; v.f = f;
    unsigned r = v.u + 0x7fffu + ((v.u >> 16) & 1u);   // RNE (inputs finite)
    return (unsigned short)(r >> 16);
}

__device__ inline float fast_tanh(float x) {
    float e2 = __expf(2.0f * x);
    return (e2 - 1.0f) * __builtin_amdgcn_rcpf(e2 + 1.0f);
}

// HBM -> LDS direct, 16B per lane (emits global_load_lds_dwordx4).
// LDS dest semantics: wave-uniform base + lane*16 — our layout is exactly
// linear in thread order, so per-lane dst pointers match the HW pattern.
__device__ inline void async16(const void* g, void* l) {
    __builtin_amdgcn_global_load_lds(
        (const __attribute__((address_space(1))) unsigned int*)g,
        (__attribute__((address_space(3))) unsigned int*)l, 16, 0, 0);
}

// ---------------------------------------------------------------------------
// m97-structure GEMM: 128x128 C-tile, BK=32, linear LDS [128][32] bf16 (8KB),
// global_load_lds staging, 2 barriers per k-step, 4 waves x 4x4 16x16x32 MFMA.
// ---------------------------------------------------------------------------
#define GEMM_PROLOG(COLT)                                                    \
    __shared__ short As[128 * 32];                                           \
    __shared__ short Bs[128 * 32];                                           \
    const int bcol = (blockIdx.x % (COLT)) * 128;                            \
    const int brow = (blockIdx.x / (COLT)) * 128;                            \
    const int t = threadIdx.x, lane = t & 63, wid = t >> 6;                  \
    const int wr = (wid >> 1) * 64, wc = (wid & 1) * 64;                     \
    const int l15 = lane & 15, lk8 = (lane >> 4) * 8;                        \
    const int strow = t >> 2, skb = (t & 3) * 8;                             \
    short* al0 = &As[t * 8];                                                 \
    short* al1 = &As[2048 + t * 8];                                          \
    short* bl0 = &Bs[t * 8];                                                 \
    short* bl1 = &Bs[2048 + t * 8];                                          \
    f32x4 acc[4][4] = {};

#define MFMA_TILE_CORE()                                                     \
    {                                                                        \
        bf16x8 afr[4], bfr[4];                                               \
        _Pragma("unroll")                                                    \
        for (int m = 0; m < 4; ++m)                                          \
            afr[m] = *(const bf16x8*)&As[(wr + m * 16 + l15) * 32 + lk8];    \
        _Pragma("unroll")                                                    \
        for (int n = 0; n < 4; ++n)                                          \
            bfr[n] = *(const bf16x8*)&Bs[(wc + n * 16 + l15) * 32 + lk8];    \
        _Pragma("unroll")                                                    \
        for (int m = 0; m < 4; ++m)                                          \
            _Pragma("unroll")                                                \
            for (int n = 0; n < 4; ++n)                                      \
                acc[m][n] = __builtin_amdgcn_mfma_f32_16x16x32_bf16(         \
                    afr[m], bfr[n], acc[m][n], 0, 0, 0);                     \
    }

// A, B both [rows][K] bf16, K-contiguous. ag/bg = this thread's staging rows.
#define GEMM_KLOOP(KTOT, APTR, BPTR, K)                                      \
    {                                                                        \
        const short* ag0 = (APTR) + (size_t)(brow + strow) * (K) + skb;      \
        const short* ag1 = (APTR) + (size_t)(brow + strow + 64) * (K) + skb; \
        const short* bg0 = (BPTR) + (size_t)(bcol + strow) * (K) + skb;      \
        const short* bg1 = (BPTR) + (size_t)(bcol + strow + 64) * (K) + skb; \
        for (int k0 = 0; k0 < (KTOT); k0 += 32) {                            \
            __syncthreads();                                                 \
            async16(ag0 + k0, al0);                                          \
            async16(ag1 + k0, al1);                                          \
            async16(bg0 + k0, bl0);                                          \
            async16(bg1 + k0, bl1);                                          \
            __syncthreads();                                                 \
            MFMA_TILE_CORE();                                                \
        }                                                                    \
    }

// Pure bf16 GEMM: C[M][N] = A[M][K] @ B[N][K]^T.  EPI 0: store; 1: tanh(x+bias)
template<int M, int N, int K, int EPI>
__global__ __launch_bounds__(256) void k_gemm(
    const short* __restrict__ A, const short* __restrict__ B,
    const float* __restrict__ bias, float* __restrict__ C)
{
    GEMM_PROLOG(N / 128);
    GEMM_KLOOP(K, A, B, K);
    #pragma unroll
    for (int m = 0; m < 4; ++m)
        #pragma unroll
        for (int n = 0; n < 4; ++n) {
            int col = bcol + wc + n * 16 + l15;
            int row = brow + wr + m * 16 + (lane >> 4) * 4;
            float bv = (EPI == 1) ? bias[col] : 0.0f;
            #pragma unroll
            for (int r = 0; r < 4; ++r) {
                float v = acc[m][n][r] + bv;
                if (EPI == 1) v = fast_tanh(v);
                C[(size_t)(row + r) * N + col] = v;
            }
        }
}

// state = tanh(tS @ W_s + cS @ W_c): two K-phases into one accumulator.
__global__ __launch_bounds__(256) void k_state_gemm(
    const short* __restrict__ tS, const short* __restrict__ cS,
    const short* __restrict__ WsT, const short* __restrict__ WcT,
    float* __restrict__ state)
{
    GEMM_PROLOG(DD / 128);
    GEMM_KLOOP(DD, tS, WsT, DD);
    GEMM_KLOOP(DD, cS, WcT, DD);
    #pragma unroll
    for (int m = 0; m < 4; ++m)
        #pragma unroll
        for (int n = 0; n < 4; ++n) {
            int col = bcol + wc + n * 16 + l15;
            int row = brow + wr + m * 16 + (lane >> 4) * 4;
            #pragma unroll
            for (int r = 0; r < 4; ++r)
                state[(size_t)(row + r) * DD + col] = fast_tanh(acc[m][n][r]);
        }
}

// All five weight transposes fused: fp32 [R][C] -> bf16 [C][R]
__global__ __launch_bounds__(256) void k_transpose_all(
    const float* __restrict__ We, const float* __restrict__ Ws,
    const float* __restrict__ Wc, const float* __restrict__ Wch,
    const float* __restrict__ Wtg,
    short* eT, short* sT, short* cT, short* chT, short* tgT)
{
    __shared__ float ls[32][33];
    int b = blockIdx.x;
    const float* in; short* out; int C;
    if      (b < 576)  { in = We;  out = eT;  C = 768; }
    else if (b < 1152) { in = Ws;  out = sT;  C = 768; b -= 576; }
    else if (b < 1728) { in = Wc;  out = cT;  C = 768; b -= 1152; }
    else if (b < 2112) { in = Wch; out = chT; C = 512; b -= 1728; }
    else               { in = Wtg; out = tgT; C = 512; b -= 2112; }
    const int R = 768;
    int ct = C / 32;
    int bx = b % ct, by = b / ct;
    int t = threadIdx.x;
    int c = t & 31, r0 = (t >> 5) * 4;
    #pragma unroll
    for (int i = 0; i < 4; ++i)
        ls[r0 + i][c] = in[(size_t)(by * 32 + r0 + i) * C + bx * 32 + c];
    __syncthreads();
    int cc = t >> 3, rb = (t & 7) * 4;
    ushort4 v;
    v.x = f2bf(ls[rb + 0][cc]);
    v.y = f2bf(ls[rb + 1][cc]);
    v.z = f2bf(ls[rb + 2][cc]);
    v.w = f2bf(ls[rb + 3][cc]);
    *(ushort4*)&out[(size_t)(bx * 32 + cc) * R + by * 32 + rb] = v;
}

// A_ctx[i][k] = bf16(xemb[xtokens[i]][k])   (8 elems/thread)
__global__ __launch_bounds__(256) void k_prep_ctx(
    const float* __restrict__ xemb, const int* __restrict__ xtokens,
    short* __restrict__ A)
{
    int e = (blockIdx.x * 256 + threadIdx.x) * 8;
    int i = e / DD, k = e % DD;
    const float* src = xemb + (size_t)xtokens[i] * DD + k;
    float4 v0 = ((const float4*)src)[0];
    float4 v1 = ((const float4*)src)[1];
    bf16x8 p;
    p[0] = f2bf(v0.x); p[1] = f2bf(v0.y); p[2] = f2bf(v0.z); p[3] = f2bf(v0.w);
    p[4] = f2bf(v1.x); p[5] = f2bf(v1.y); p[6] = f2bf(v1.z); p[7] = f2bf(v1.w);
    *(bf16x8*)(A + e) = p;
}

// A[i][k] = bf16(tanh(state[i/PF][k] + pos[i%PF][k] + emb[tgt[i]][k]))
template<int PF>
__global__ __launch_bounds__(256) void k_prep_score(
    const float* __restrict__ state, const float* __restrict__ pos,
    const float* __restrict__ emb, const int* __restrict__ tgt,
    short* __restrict__ A)
{
    int e = (blockIdx.x * 256 + threadIdx.x) * 8;
    int i = e / DD, k = e % DD;
    const float* sp = state + (size_t)(i / PF) * DD + k;
    const float* pp = pos + (size_t)(i % PF) * DD + k;
    const float* ep = emb + (size_t)tgt[i] * DD + k;
    bf16x8 q;
    #pragma unroll
    for (int h = 0; h < 2; ++h) {
        float4 s = ((const float4*)sp)[h];
        float4 p = ((const float4*)pp)[h];
        float4 ev = ((const float4*)ep)[h];
        q[h * 4 + 0] = f2bf(fast_tanh(s.x + p.x + ev.x));
        q[h * 4 + 1] = f2bf(fast_tanh(s.y + p.y + ev.y));
        q[h * 4 + 2] = f2bf(fast_tanh(s.z + p.z + ev.z));
        q[h * 4 + 3] = f2bf(fast_tanh(s.w + p.w + ev.w));
    }
    *(bf16x8*)(A + e) = q;
}

// Segment means over contiguous segments (tok_ids nondecreasing) -> bf16.
__global__ __launch_bounds__(256) void k_segsum(
    const int* __restrict__ tokens, const float* __restrict__ token_ctx,
    const float* __restrict__ char_emb,
    short* __restrict__ tS, short* __restrict__ cS)
{
    int j = blockIdx.x;
    int lo = 0, hi = NN;
    while (lo < hi) { int mid = (lo + hi) >> 1; if (tokens[mid * 3] < j + 1) lo = mid + 1; else hi = mid; }
    int start = lo;
    hi = NN;
    while (lo < hi) { int mid = (lo + hi) >> 1; if (tokens[mid * 3] < j + 2) lo = mid + 1; else hi = mid; }
    int end = lo;

    float accT[3] = {0.f, 0.f, 0.f}, accC[3] = {0.f, 0.f, 0.f};
    for (int i = start; i < end; ++i) {
        int xid = tokens[i * 3 + 1];
        int cid = tokens[i * 3 + 2];
        const float* tr = token_ctx + (size_t)xid * DD;
        const float* cr = char_emb + (size_t)cid * DD;
        #pragma unroll
        for (int q = 0; q < 3; ++q) {
            int d = threadIdx.x + q * 256;
            accT[q] += tr[d];
            accC[q] += cr[d];
        }
    }
    float inv = 1.0f / (float)(end - start);
    #pragma unroll
    for (int q = 0; q < 3; ++q) {
        int d = threadIdx.x + q * 256;
        tS[(size_t)j * DD + d] = (short)f2bf(accT[q] * inv);
        cS[(size_t)j * DD + d] = (short)f2bf(accC[q] * inv);
    }
}

extern "C" void kernel_launch(void* const* d_in, const int* in_sizes, int n_in,
                              void* d_out, int out_size, void* d_ws, size_t ws_size,
                              hipStream_t stream)
{
    const int*   xtokens  = (const int*)d_in[0];
    const int*   tokens   = (const int*)d_in[1];
    const int*   tfc      = (const int*)d_in[5];
    const int*   ttg      = (const int*)d_in[6];
    const float* xemb     = (const float*)d_in[7];
    const float* W_enc    = (const float*)d_in[8];
    const float* b_enc    = (const float*)d_in[9];
    const float* char_emb = (const float*)d_in[10];
    const float* tag_emb  = (const float*)d_in[11];
    const float* W_s      = (const float*)d_in[12];
    const float* W_c      = (const float*)d_in[13];
    const float* form_pos = (const float*)d_in[14];
    const float* tag_pos  = (const float*)d_in[15];
    const float* W_char   = (const float*)d_in[16];
    const float* W_tag    = (const float*)d_in[17];
    float* out = (float*)d_out;
    float* ws  = (float*)d_ws;

    // ws layout (~87 MB; ws_size ~600 MB per round-4 fill profile: 603084 KB poison)
    float* token_ctx = ws;                          // 8192x768 f32
    float* state     = ws +  6291456;               // 1024x768 f32
    short* tS_bf     = (short*)(ws +  7077888);     // 1024x768 bf16
    short* cS_bf     = (short*)(ws +  7471104);     // 1024x768 bf16
    short* W_encT    = (short*)(ws +  7864320);     // 768x768  bf16 [N][K]
    short* W_sT      = (short*)(ws +  8159232);
    short* W_cT      = (short*)(ws +  8454144);
    short* W_charT   = (short*)(ws +  8749056);     // 512x768  bf16
    short* W_tagT    = (short*)(ws +  8945664);     // 512x768  bf16
    short* A_ctx     = (short*)(ws +  9142272);     // 8192x768  bf16
    short* A_f       = (short*)(ws + 12288000);     // 16384x768 bf16
    short* A_t       = (short*)(ws + 18579456);     // 8192x768  bf16

    hipLaunchKernelGGL(k_transpose_all, dim3(2496), dim3(256), 0, stream,
                       W_enc, W_s, W_c, W_char, W_tag,
                       W_encT, W_sT, W_cT, W_charT, W_tagT);
    hipLaunchKernelGGL(k_prep_ctx, dim3(NN * DD / 2048), dim3(256), 0, stream,
                       xemb, xtokens, A_ctx);
    hipLaunchKernelGGL((k_gemm<NN, DD, DD, 1>), dim3((NN/128)*(DD/128)), dim3(256), 0, stream,
                       A_ctx, W_encT, b_enc, token_ctx);
    hipLaunchKernelGGL(k_segsum, dim3(TT), dim3(256), 0, stream,
                       tokens, token_ctx, char_emb, tS_bf, cS_bf);
    hipLaunchKernelGGL(k_state_gemm, dim3((TT/128)*(DD/128)), dim3(256), 0, stream,
                       tS_bf, cS_bf, W_sT, W_cT, state);
    hipLaunchKernelGGL((k_prep_score<FF>), dim3(TT * FF * DD / 2048), dim3(256), 0, stream,
                       state, form_pos, char_emb, tfc, A_f);
    hipLaunchKernelGGL((k_gemm<TT * FF, CVV, DD, 0>), dim3((TT*FF/128)*(CVV/128)), dim3(256), 0, stream,
                       A_f, W_charT, nullptr, out);
    hipLaunchKernelGGL((k_prep_score<LL>), dim3(TT * LL * DD / 2048), dim3(256), 0, stream,
                       state, tag_pos, tag_emb, ttg, A_t);
    hipLaunchKernelGGL((k_gemm<TT * LL, TVV, DD, 0>), dim3((TT*LL/128)*(TVV/128)), dim3(256), 0, stream,
                       A_t, W_tagT, nullptr, out + (size_t)TT * FF * CVV);
}

// Round 7
// 348.891 us; speedup vs baseline: 1.0485x; 1.0485x over previous
//
#include <hip/hip_runtime.h>
#include <hip/hip_bf16.h>

#define DD 768
#define NN 8192
#define TT 1024
#define FF 16
#define LL 8
#define CVV 512
#define TVV 512

typedef __attribute__((ext_vector_type(8))) short bf16x8;
typedef __attribute__((ext_vector_type(4))) float f32x4;

__device__ inline unsigned short f2bf(float f) {
    union { float f; unsigned u; } v; v.f = f;
    unsigned r = v.u + 0x7fffu + ((v.u >> 16) & 1u);   // RNE (inputs finite)
    return (unsigned short)(r >> 16);
}

__device__ inline float fast_tanh(float x) {
    float e2 = __expf(2.0f * x);
    return (e2 - 1.0f) * __builtin_amdgcn_rcpf(e2 + 1.0f);
}

// HBM -> LDS direct, 16B per lane (global_load_lds_dwordx4).
__device__ inline void async16(const void* g, void* l) {
    __builtin_amdgcn_global_load_lds(
        (const __attribute__((address_space(1))) unsigned int*)g,
        (__attribute__((address_space(3))) unsigned int*)l, 16, 0, 0);
}

// ---------------------------------------------------------------------------
// 2-phase double-buffered GEMM: 128x128 C-tile, BK=32, LDS [2][128][32] bf16
// per operand (32 KB). Per k-step: {STAGE next into buf^1 ; MFMA on buf ;
// __syncthreads()} — ONE barrier per step, next-tile loads overlap MFMA.
// Safe by construction: __syncthreads drains vmcnt(0), so every buffer is
// fully resident before any wave reads it, and fully read before overwrite.
// ---------------------------------------------------------------------------
#define GEMM_PROLOG(COLT)                                                    \
    __shared__ short As[2][128 * 32];                                        \
    __shared__ short Bs[2][128 * 32];                                        \
    const int bcol = (blockIdx.x % (COLT)) * 128;                            \
    const int brow = (blockIdx.x / (COLT)) * 128;                            \
    const int t = threadIdx.x, lane = t & 63, wid = t >> 6;                  \
    const int wr = (wid >> 1) * 64, wc = (wid & 1) * 64;                     \
    const int l15 = lane & 15, lk8 = (lane >> 4) * 8;                        \
    const int strow = t >> 2, skb = (t & 3) * 8;                             \
    f32x4 acc[4][4] = {};

#define STAGE_AB(c, k0)                                                      \
    async16(ag0 + (k0), &As[c][t * 8]);                                      \
    async16(ag1 + (k0), &As[c][2048 + t * 8]);                               \
    async16(bg0 + (k0), &Bs[c][t * 8]);                                      \
    async16(bg1 + (k0), &Bs[c][2048 + t * 8]);

#define MFMA_TILE_CORE(c)                                                    \
    {                                                                        \
        bf16x8 afr[4], bfr[4];                                               \
        _Pragma("unroll")                                                    \
        for (int m = 0; m < 4; ++m)                                          \
            afr[m] = *(const bf16x8*)&As[c][(wr + m * 16 + l15) * 32 + lk8]; \
        _Pragma("unroll")                                                    \
        for (int n = 0; n < 4; ++n)                                          \
            bfr[n] = *(const bf16x8*)&Bs[c][(wc + n * 16 + l15) * 32 + lk8]; \
        _Pragma("unroll")                                                    \
        for (int m = 0; m < 4; ++m)                                          \
            _Pragma("unroll")                                                \
            for (int n = 0; n < 4; ++n)                                      \
                acc[m][n] = __builtin_amdgcn_mfma_f32_16x16x32_bf16(         \
                    afr[m], bfr[n], acc[m][n], 0, 0, 0);                     \
    }

// A, B both [rows][K] bf16, K-contiguous.
#define GEMM_KLOOP(KTOT, APTR, BPTR, K)                                      \
    {                                                                        \
        const short* ag0 = (APTR) + (size_t)(brow + strow) * (K) + skb;      \
        const short* ag1 = (APTR) + (size_t)(brow + strow + 64) * (K) + skb; \
        const short* bg0 = (BPTR) + (size_t)(bcol + strow) * (K) + skb;      \
        const short* bg1 = (BPTR) + (size_t)(bcol + strow + 64) * (K) + skb; \
        STAGE_AB(0, 0);                                                      \
        __syncthreads();                                                     \
        int cur = 0;                                                         \
        for (int k0 = 0; k0 < (KTOT); k0 += 32) {                            \
            if (k0 + 32 < (KTOT)) { STAGE_AB(cur ^ 1, k0 + 32); }            \
            MFMA_TILE_CORE(cur);                                             \
            __syncthreads();                                                 \
            cur ^= 1;                                                        \
        }                                                                    \
    }

#define GEMM_EPILOG(NV, DST, DO_TANH, BIASP)                                 \
    _Pragma("unroll")                                                        \
    for (int m = 0; m < 4; ++m)                                              \
        _Pragma("unroll")                                                    \
        for (int n = 0; n < 4; ++n) {                                        \
            int col = bcol + wc + n * 16 + l15;                              \
            int row = brow + wr + m * 16 + (lane >> 4) * 4;                  \
            float bv = (DO_TANH && (BIASP)) ? ((const float*)(BIASP))[col] : 0.0f; \
            _Pragma("unroll")                                                \
            for (int r = 0; r < 4; ++r) {                                    \
                float v = acc[m][n][r] + bv;                                 \
                if (DO_TANH) v = fast_tanh(v);                               \
                (DST)[(size_t)(row + r) * (NV) + col] = v;                   \
            }                                                                \
        }

// token_ctx = tanh(A_ctx @ W_encT^T + b)   M=8192 N=768 K=768
__global__ __launch_bounds__(256) void k_gemm_ctx(
    const short* __restrict__ A, const short* __restrict__ B,
    const float* __restrict__ bias, float* __restrict__ C)
{
    GEMM_PROLOG(DD / 128);
    GEMM_KLOOP(DD, A, B, DD);
    GEMM_EPILOG(DD, C, 1, bias);
}

// state = tanh(tS @ W_s + cS @ W_c): two K-phases into one accumulator.
__global__ __launch_bounds__(256) void k_state_gemm(
    const short* __restrict__ tS, const short* __restrict__ cS,
    const short* __restrict__ WsT, const short* __restrict__ WcT,
    float* __restrict__ state)
{
    GEMM_PROLOG(DD / 128);
    GEMM_KLOOP(DD, tS, WsT, DD);
    GEMM_KLOOP(DD, cS, WcT, DD);
    GEMM_EPILOG(DD, state, 1, (const float*)nullptr);
}

// Fused score GEMM: rows [0,16384) -> W_charT, rows [16384,24576) -> W_tagT.
// A rows and output rows are contiguous across both regions.
__global__ __launch_bounds__(256) void k_gemm_scores(
    const short* __restrict__ A, const short* __restrict__ Bch,
    const short* __restrict__ Btg, float* __restrict__ C)
{
    GEMM_PROLOG(CVV / 128);
    const short* B = (brow >= TT * FF) ? Btg : Bch;
    GEMM_KLOOP(DD, A, B, DD);
    GEMM_EPILOG(CVV, C, 0, (const float*)nullptr);
}

// Fused front: blocks [0,2496) = five weight transposes fp32[R][C]->bf16[C][R];
// blocks [2496,5568) = A_ctx gather-convert.
__global__ __launch_bounds__(256) void k_front(
    const float* __restrict__ We, const float* __restrict__ Ws,
    const float* __restrict__ Wc, const float* __restrict__ Wch,
    const float* __restrict__ Wtg,
    short* eT, short* sT, short* cT, short* chT, short* tgT,
    const float* __restrict__ xemb, const int* __restrict__ xtokens,
    short* __restrict__ A)
{
    __shared__ float ls[32][33];
    int b = blockIdx.x;
    int t = threadIdx.x;
    if (b < 2496) {
        const float* in; short* out; int C;
        if      (b < 576)  { in = We;  out = eT;  C = 768; }
        else if (b < 1152) { in = Ws;  out = sT;  C = 768; b -= 576; }
        else if (b < 1728) { in = Wc;  out = cT;  C = 768; b -= 1152; }
        else if (b < 2112) { in = Wch; out = chT; C = 512; b -= 1728; }
        else               { in = Wtg; out = tgT; C = 512; b -= 2112; }
        const int R = 768;
        int ct = C / 32;
        int bx = b % ct, by = b / ct;
        int c = t & 31, r0 = (t >> 5) * 4;
        #pragma unroll
        for (int i = 0; i < 4; ++i)
            ls[r0 + i][c] = in[(size_t)(by * 32 + r0 + i) * C + bx * 32 + c];
        __syncthreads();
        int cc = t >> 3, rb = (t & 7) * 4;
        ushort4 v;
        v.x = f2bf(ls[rb + 0][cc]);
        v.y = f2bf(ls[rb + 1][cc]);
        v.z = f2bf(ls[rb + 2][cc]);
        v.w = f2bf(ls[rb + 3][cc]);
        *(ushort4*)&out[(size_t)(bx * 32 + cc) * R + by * 32 + rb] = v;
    } else {
        int e = ((b - 2496) * 256 + t) * 8;
        int i = e / DD, k = e % DD;
        const float* src = xemb + (size_t)xtokens[i] * DD + k;
        float4 v0 = ((const float4*)src)[0];
        float4 v1 = ((const float4*)src)[1];
        bf16x8 p;
        p[0] = f2bf(v0.x); p[1] = f2bf(v0.y); p[2] = f2bf(v0.z); p[3] = f2bf(v0.w);
        p[4] = f2bf(v1.x); p[5] = f2bf(v1.y); p[6] = f2bf(v1.z); p[7] = f2bf(v1.w);
        *(bf16x8*)(A + e) = p;
    }
}

// Fused prep for both score A-panels: rows [0,16384)=form, [16384,24576)=tag.
__global__ __launch_bounds__(256) void k_prep_scores(
    const float* __restrict__ state,
    const float* __restrict__ form_pos, const float* __restrict__ tag_pos,
    const float* __restrict__ char_emb, const float* __restrict__ tag_emb,
    const int* __restrict__ tfc, const int* __restrict__ ttg,
    short* __restrict__ A)
{
    int e = (blockIdx.x * 256 + threadIdx.x) * 8;
    int i = e / DD, k = e % DD;
    const float *sp, *pp, *ep;
    if (i < TT * FF) {
        sp = state + (size_t)(i / FF) * DD + k;
        pp = form_pos + (size_t)(i % FF) * DD + k;
        ep = char_emb + (size_t)tfc[i] * DD + k;
    } else {
        int j = i - TT * FF;
        sp = state + (size_t)(j / LL) * DD + k;
        pp = tag_pos + (size_t)(j % LL) * DD + k;
        ep = tag_emb + (size_t)ttg[j] * DD + k;
    }
    bf16x8 q;
    #pragma unroll
    for (int h = 0; h < 2; ++h) {
        float4 s = ((const float4*)sp)[h];
        float4 p = ((const float4*)pp)[h];
        float4 ev = ((const float4*)ep)[h];
        q[h * 4 + 0] = f2bf(fast_tanh(s.x + p.x + ev.x));
        q[h * 4 + 1] = f2bf(fast_tanh(s.y + p.y + ev.y));
        q[h * 4 + 2] = f2bf(fast_tanh(s.z + p.z + ev.z));
        q[h * 4 + 3] = f2bf(fast_tanh(s.w + p.w + ev.w));
    }
    *(bf16x8*)(A + e) = q;
}

// Segment means over contiguous segments (tok_ids nondecreasing) -> bf16.
__global__ __launch_bounds__(256) void k_segsum(
    const int* __restrict__ tokens, const float* __restrict__ token_ctx,
    const float* __restrict__ char_emb,
    short* __restrict__ tS, short* __restrict__ cS)
{
    int j = blockIdx.x;
    int lo = 0, hi = NN;
    while (lo < hi) { int mid = (lo + hi) >> 1; if (tokens[mid * 3] < j + 1) lo = mid + 1; else hi = mid; }
    int start = lo;
    hi = NN;
    while (lo < hi) { int mid = (lo + hi) >> 1; if (tokens[mid * 3] < j + 2) lo = mid + 1; else hi = mid; }
    int end = lo;

    float accT[3] = {0.f, 0.f, 0.f}, accC[3] = {0.f, 0.f, 0.f};
    for (int i = start; i < end; ++i) {
        int xid = tokens[i * 3 + 1];
        int cid = tokens[i * 3 + 2];
        const float* tr = token_ctx + (size_t)xid * DD;
        const float* cr = char_emb + (size_t)cid * DD;
        #pragma unroll
        for (int q = 0; q < 3; ++q) {
            int d = threadIdx.x + q * 256;
            accT[q] += tr[d];
            accC[q] += cr[d];
        }
    }
    float inv = 1.0f / (float)(end - start);
    #pragma unroll
    for (int q = 0; q < 3; ++q) {
        int d = threadIdx.x + q * 256;
        tS[(size_t)j * DD + d] = (short)f2bf(accT[q] * inv);
        cS[(size_t)j * DD + d] = (short)f2bf(accC[q] * inv);
    }
}

extern "C" void kernel_launch(void* const* d_in, const int* in_sizes, int n_in,
                              void* d_out, int out_size, void* d_ws, size_t ws_size,
                              hipStream_t stream)
{
    const int*   xtokens  = (const int*)d_in[0];
    const int*   tokens   = (const int*)d_in[1];
    const int*   tfc      = (const int*)d_in[5];
    const int*   ttg      = (const int*)d_in[6];
    const float* xemb     = (const float*)d_in[7];
    const float* W_enc    = (const float*)d_in[8];
    const float* b_enc    = (const float*)d_in[9];
    const float* char_emb = (const float*)d_in[10];
    const float* tag_emb  = (const float*)d_in[11];
    const float* W_s      = (const float*)d_in[12];
    const float* W_c      = (const float*)d_in[13];
    const float* form_pos = (const float*)d_in[14];
    const float* tag_pos  = (const float*)d_in[15];
    const float* W_char   = (const float*)d_in[16];
    const float* W_tag    = (const float*)d_in[17];
    float* out = (float*)d_out;
    float* ws  = (float*)d_ws;

    // ws layout (~87 MB of ~600 MB; same as round-5/6 proven layout).
    float* token_ctx = ws;                          // 8192x768 f32
    float* state     = ws +  6291456;               // 1024x768 f32
    short* tS_bf     = (short*)(ws +  7077888);     // 1024x768 bf16
    short* cS_bf     = (short*)(ws +  7471104);     // 1024x768 bf16
    short* W_encT    = (short*)(ws +  7864320);     // 768x768  bf16 [N][K]
    short* W_sT      = (short*)(ws +  8159232);
    short* W_cT      = (short*)(ws +  8454144);
    short* W_charT   = (short*)(ws +  8749056);     // 512x768  bf16
    short* W_tagT    = (short*)(ws +  8945664);     // 512x768  bf16 (contiguous after W_charT)
    short* A_ctx     = (short*)(ws +  9142272);     // 8192x768  bf16
    short* A_sc      = (short*)(ws + 12288000);     // 24576x768 bf16 (form rows then tag rows)

    hipLaunchKernelGGL(k_front, dim3(5568), dim3(256), 0, stream,
                       W_enc, W_s, W_c, W_char, W_tag,
                       W_encT, W_sT, W_cT, W_charT, W_tagT,
                       xemb, xtokens, A_ctx);
    hipLaunchKernelGGL(k_gemm_ctx, dim3((NN/128)*(DD/128)), dim3(256), 0, stream,
                       A_ctx, W_encT, b_enc, token_ctx);
    hipLaunchKernelGGL(k_segsum, dim3(TT), dim3(256), 0, stream,
                       tokens, token_ctx, char_emb, tS_bf, cS_bf);
    hipLaunchKernelGGL(k_state_gemm, dim3((TT/128)*(DD/128)), dim3(256), 0, stream,
                       tS_bf, cS_bf, W_sT, W_cT, state);
    hipLaunchKernelGGL(k_prep_scores, dim3((TT*(FF+LL)) * DD / 2048), dim3(256), 0, stream,
                       state, form_pos, tag_pos, char_emb, tag_emb, tfc, ttg, A_sc);
    hipLaunchKernelGGL(k_gemm_scores, dim3((TT*(FF+LL)/128)*(CVV/128)), dim3(256), 0, stream,
                       A_sc, W_charT, W_tagT, out);
}

// Round 8
// 344.283 us; speedup vs baseline: 1.0626x; 1.0134x over previous
//
#include <hip/hip_runtime.h>
#include <hip/hip_bf16.h>

#define DD 768
#define NN 8192
#define TT 1024
#define FF 16
#define LL 8
#define CVV 512
#define TVV 512

typedef __attribute__((ext_vector_type(8))) short bf16x8;
typedef __attribute__((ext_vector_type(4))) float f32x4;

__device__ inline unsigned short f2bf(float f) {
    union { float f; unsigned u; } v; v.f = f;
    unsigned r = v.u + 0x7fffu + ((v.u >> 16) & 1u);   // RNE (inputs finite)
    return (unsigned short)(r >> 16);
}

__device__ inline float fast_tanh(float x) {
    float e2 = __expf(2.0f * x);
    return (e2 - 1.0f) * __builtin_amdgcn_rcpf(e2 + 1.0f);
}

// HBM -> LDS direct, 16B per lane (global_load_lds_dwordx4).
__device__ inline void async16(const void* g, void* l) {
    __builtin_amdgcn_global_load_lds(
        (const __attribute__((address_space(1))) unsigned int*)g,
        (__attribute__((address_space(3))) unsigned int*)l, 16, 0, 0);
}

// ---------------------------------------------------------------------------
// Counted-vmcnt double-buffered GEMM (T4 on 2-phase): 128x128 C-tile, BK=32,
// LDS [2][128][32] bf16 per operand. Loads for tile k+1 stay IN FLIGHT across
// barriers (s_waitcnt vmcnt(4), never a full drain in the loop).
// Safety: barrier1+vmcnt(4) => tile k resident before reads; per-wave
// lgkmcnt(0)+barrier2 => all waves' frag reads in regs before buf overwrite.
// ---------------------------------------------------------------------------
#define GEMM_PROLOG(COLT)                                                    \
    __shared__ short As[2][128 * 32];                                        \
    __shared__ short Bs[2][128 * 32];                                        \
    const int bcol = (blockIdx.x % (COLT)) * 128;                            \
    const int brow = (blockIdx.x / (COLT)) * 128;                            \
    const int t = threadIdx.x, lane = t & 63, wid = t >> 6;                  \
    const int wr = (wid >> 1) * 64, wc = (wid & 1) * 64;                     \
    const int l15 = lane & 15, lk8 = (lane >> 4) * 8;                        \
    f32x4 acc[4][4] = {};

#define STAGE_AB(c, k0)                                                      \
    async16(ag0 + (k0), &As[c][t * 8]);                                      \
    async16(ag1 + (k0), &As[c][2048 + t * 8]);                               \
    async16(bg0 + (k0), &Bs[c][t * 8]);                                      \
    async16(bg1 + (k0), &Bs[c][2048 + t * 8]);

#define GEMM_KLOOP(KTOT, APTR, BPTR, K)                                      \
    {                                                                        \
        const int strow = t >> 2, skb = (t & 3) * 8;                         \
        const short* ag0 = (APTR) + (size_t)(brow + strow) * (K) + skb;      \
        const short* ag1 = (APTR) + (size_t)(brow + strow + 64) * (K) + skb; \
        const short* bg0 = (BPTR) + (size_t)(bcol + strow) * (K) + skb;      \
        const short* bg1 = (BPTR) + (size_t)(bcol + strow + 64) * (K) + skb; \
        const int KT = (KTOT) / 32;                                          \
        STAGE_AB(0, 0);                                                      \
        STAGE_AB(1, 32);                                                     \
        _Pragma("unroll 2")                                                  \
        for (int kt = 0; kt < KT; ++kt) {                                    \
            const int c = kt & 1;                                            \
            if (kt + 1 < KT) {                                               \
                asm volatile("s_waitcnt vmcnt(4)" ::: "memory");             \
            } else {                                                         \
                asm volatile("s_waitcnt vmcnt(0)" ::: "memory");             \
            }                                                                \
            __builtin_amdgcn_s_barrier();                                    \
            bf16x8 afr[4], bfr[4];                                           \
            _Pragma("unroll")                                                \
            for (int m = 0; m < 4; ++m)                                      \
                afr[m] = *(const bf16x8*)&As[c][(wr + m * 16 + l15) * 32 + lk8]; \
            _Pragma("unroll")                                                \
            for (int n = 0; n < 4; ++n)                                      \
                bfr[n] = *(const bf16x8*)&Bs[c][(wc + n * 16 + l15) * 32 + lk8]; \
            asm volatile("s_waitcnt lgkmcnt(0)" ::: "memory");               \
            __builtin_amdgcn_sched_barrier(0);                               \
            __builtin_amdgcn_s_barrier();                                    \
            if (kt + 2 < KT) { STAGE_AB(c, (kt + 2) * 32); }                 \
            __builtin_amdgcn_sched_barrier(0);                               \
            _Pragma("unroll")                                                \
            for (int m = 0; m < 4; ++m)                                      \
                _Pragma("unroll")                                            \
                for (int n = 0; n < 4; ++n)                                  \
                    acc[m][n] = __builtin_amdgcn_mfma_f32_16x16x32_bf16(     \
                        afr[m], bfr[n], acc[m][n], 0, 0, 0);                 \
        }                                                                    \
    }

#define GEMM_EPILOG(NV, DST, DO_TANH, BIASP)                                 \
    _Pragma("unroll")                                                        \
    for (int m = 0; m < 4; ++m)                                              \
        _Pragma("unroll")                                                    \
        for (int n = 0; n < 4; ++n) {                                        \
            int col = bcol + wc + n * 16 + l15;                              \
            int row = brow + wr + m * 16 + (lane >> 4) * 4;                  \
            float bv = (DO_TANH && (BIASP)) ? ((const float*)(BIASP))[col] : 0.0f; \
            _Pragma("unroll")                                                \
            for (int r = 0; r < 4; ++r) {                                    \
                float v = acc[m][n][r] + bv;                                 \
                if (DO_TANH) v = fast_tanh(v);                               \
                (DST)[(size_t)(row + r) * (NV) + col] = v;                   \
            }                                                                \
        }

// token_ctx = tanh(A_ctx @ W_encT^T + b)   M=8192 N=768 K=768
__global__ __launch_bounds__(256) void k_gemm_ctx(
    const short* __restrict__ A, const short* __restrict__ B,
    const float* __restrict__ bias, float* __restrict__ C)
{
    GEMM_PROLOG(DD / 128);
    GEMM_KLOOP(DD, A, B, DD);
    GEMM_EPILOG(DD, C, 1, bias);
}

// state = tanh(tS @ W_s + cS @ W_c): two K-phases into one accumulator.
// Phase-2's first STAGE targets buf[0], which every wave finished reading
// before phase-1's final barrier pair — no cross-phase hazard.
__global__ __launch_bounds__(256) void k_state_gemm(
    const short* __restrict__ tS, const short* __restrict__ cS,
    const short* __restrict__ WsT, const short* __restrict__ WcT,
    float* __restrict__ state)
{
    GEMM_PROLOG(DD / 128);
    GEMM_KLOOP(DD, tS, WsT, DD);
    GEMM_KLOOP(DD, cS, WcT, DD);
    GEMM_EPILOG(DD, state, 1, (const float*)nullptr);
}

// Fused score GEMM: rows [0,16384) -> W_charT, rows [16384,24576) -> W_tagT.
__global__ __launch_bounds__(256) void k_gemm_scores(
    const short* __restrict__ A, const short* __restrict__ Bch,
    const short* __restrict__ Btg, float* __restrict__ C)
{
    GEMM_PROLOG(CVV / 128);
    const short* B = (brow >= TT * FF) ? Btg : Bch;
    GEMM_KLOOP(DD, A, B, DD);
    GEMM_EPILOG(CVV, C, 0, (const float*)nullptr);
}

// Fused front: blocks [0,2496) = five weight transposes fp32[R][C]->bf16[C][R];
// blocks [2496,5568) = A_ctx gather-convert.
__global__ __launch_bounds__(256) void k_front(
    const float* __restrict__ We, const float* __restrict__ Ws,
    const float* __restrict__ Wc, const float* __restrict__ Wch,
    const float* __restrict__ Wtg,
    short* eT, short* sT, short* cT, short* chT, short* tgT,
    const float* __restrict__ xemb, const int* __restrict__ xtokens,
    short* __restrict__ A)
{
    __shared__ float ls[32][33];
    int b = blockIdx.x;
    int t = threadIdx.x;
    if (b < 2496) {
        const float* in; short* out; int C;
        if      (b < 576)  { in = We;  out = eT;  C = 768; }
        else if (b < 1152) { in = Ws;  out = sT;  C = 768; b -= 576; }
        else if (b < 1728) { in = Wc;  out = cT;  C = 768; b -= 1152; }
        else if (b < 2112) { in = Wch; out = chT; C = 512; b -= 1728; }
        else               { in = Wtg; out = tgT; C = 512; b -= 2112; }
        const int R = 768;
        int ct = C / 32;
        int bx = b % ct, by = b / ct;
        int c = t & 31, r0 = (t >> 5) * 4;
        #pragma unroll
        for (int i = 0; i < 4; ++i)
            ls[r0 + i][c] = in[(size_t)(by * 32 + r0 + i) * C + bx * 32 + c];
        __syncthreads();
        int cc = t >> 3, rb = (t & 7) * 4;
        ushort4 v;
        v.x = f2bf(ls[rb + 0][cc]);
        v.y = f2bf(ls[rb + 1][cc]);
        v.z = f2bf(ls[rb + 2][cc]);
        v.w = f2bf(ls[rb + 3][cc]);
        *(ushort4*)&out[(size_t)(bx * 32 + cc) * R + by * 32 + rb] = v;
    } else {
        int e = ((b - 2496) * 256 + t) * 8;
        int i = e / DD, k = e % DD;
        const float* src = xemb + (size_t)xtokens[i] * DD + k;
        float4 v0 = ((const float4*)src)[0];
        float4 v1 = ((const float4*)src)[1];
        bf16x8 p;
        p[0] = f2bf(v0.x); p[1] = f2bf(v0.y); p[2] = f2bf(v0.z); p[3] = f2bf(v0.w);
        p[4] = f2bf(v1.x); p[5] = f2bf(v1.y); p[6] = f2bf(v1.z); p[7] = f2bf(v1.w);
        *(bf16x8*)(A + e) = p;
    }
}

// Fused prep for both score A-panels: rows [0,16384)=form, [16384,24576)=tag.
__global__ __launch_bounds__(256) void k_prep_scores(
    const float* __restrict__ state,
    const float* __restrict__ form_pos, const float* __restrict__ tag_pos,
    const float* __restrict__ char_emb, const float* __restrict__ tag_emb,
    const int* __restrict__ tfc, const int* __restrict__ ttg,
    short* __restrict__ A)
{
    int e = (blockIdx.x * 256 + threadIdx.x) * 8;
    int i = e / DD, k = e % DD;
    const float *sp, *pp, *ep;
    if (i < TT * FF) {
        sp = state + (size_t)(i / FF) * DD + k;
        pp = form_pos + (size_t)(i % FF) * DD + k;
        ep = char_emb + (size_t)tfc[i] * DD + k;
    } else {
        int j = i - TT * FF;
        sp = state + (size_t)(j / LL) * DD + k;
        pp = tag_pos + (size_t)(j % LL) * DD + k;
        ep = tag_emb + (size_t)ttg[j] * DD + k;
    }
    bf16x8 q;
    #pragma unroll
    for (int h = 0; h < 2; ++h) {
        float4 s = ((const float4*)sp)[h];
        float4 p = ((const float4*)pp)[h];
        float4 ev = ((const float4*)ep)[h];
        q[h * 4 + 0] = f2bf(fast_tanh(s.x + p.x + ev.x));
        q[h * 4 + 1] = f2bf(fast_tanh(s.y + p.y + ev.y));
        q[h * 4 + 2] = f2bf(fast_tanh(s.z + p.z + ev.z));
        q[h * 4 + 3] = f2bf(fast_tanh(s.w + p.w + ev.w));
    }
    *(bf16x8*)(A + e) = q;
}

// Segment means over contiguous segments (tok_ids nondecreasing) -> bf16.
__global__ __launch_bounds__(256) void k_segsum(
    const int* __restrict__ tokens, const float* __restrict__ token_ctx,
    const float* __restrict__ char_emb,
    short* __restrict__ tS, short* __restrict__ cS)
{
    int j = blockIdx.x;
    int lo = 0, hi = NN;
    while (lo < hi) { int mid = (lo + hi) >> 1; if (tokens[mid * 3] < j + 1) lo = mid + 1; else hi = mid; }
    int start = lo;
    hi = NN;
    while (lo < hi) { int mid = (lo + hi) >> 1; if (tokens[mid * 3] < j + 2) lo = mid + 1; else hi = mid; }
    int end = lo;

    float accT[3] = {0.f, 0.f, 0.f}, accC[3] = {0.f, 0.f, 0.f};
    for (int i = start; i < end; ++i) {
        int xid = tokens[i * 3 + 1];
        int cid = tokens[i * 3 + 2];
        const float* tr = token_ctx + (size_t)xid * DD;
        const float* cr = char_emb + (size_t)cid * DD;
        #pragma unroll
        for (int q = 0; q < 3; ++q) {
            int d = threadIdx.x + q * 256;
            accT[q] += tr[d];
            accC[q] += cr[d];
        }
    }
    float inv = 1.0f / (float)(end - start);
    #pragma unroll
    for (int q = 0; q < 3; ++q) {
        int d = threadIdx.x + q * 256;
        tS[(size_t)j * DD + d] = (short)f2bf(accT[q] * inv);
        cS[(size_t)j * DD + d] = (short)f2bf(accC[q] * inv);
    }
}

extern "C" void kernel_launch(void* const* d_in, const int* in_sizes, int n_in,
                              void* d_out, int out_size, void* d_ws, size_t ws_size,
                              hipStream_t stream)
{
    const int*   xtokens  = (const int*)d_in[0];
    const int*   tokens   = (const int*)d_in[1];
    const int*   tfc      = (const int*)d_in[5];
    const int*   ttg      = (const int*)d_in[6];
    const float* xemb     = (const float*)d_in[7];
    const float* W_enc    = (const float*)d_in[8];
    const float* b_enc    = (const float*)d_in[9];
    const float* char_emb = (const float*)d_in[10];
    const float* tag_emb  = (const float*)d_in[11];
    const float* W_s      = (const float*)d_in[12];
    const float* W_c      = (const float*)d_in[13];
    const float* form_pos = (const float*)d_in[14];
    const float* tag_pos  = (const float*)d_in[15];
    const float* W_char   = (const float*)d_in[16];
    const float* W_tag    = (const float*)d_in[17];
    float* out = (float*)d_out;
    float* ws  = (float*)d_ws;

    // ws layout (~87 MB of ~600 MB; same as round-5..7 proven layout).
    float* token_ctx = ws;                          // 8192x768 f32
    float* state     = ws +  6291456;               // 1024x768 f32
    short* tS_bf     = (short*)(ws +  7077888);     // 1024x768 bf16
    short* cS_bf     = (short*)(ws +  7471104);     // 1024x768 bf16
    short* W_encT    = (short*)(ws +  7864320);     // 768x768  bf16 [N][K]
    short* W_sT      = (short*)(ws +  8159232);
    short* W_cT      = (short*)(ws +  8454144);
    short* W_charT   = (short*)(ws +  8749056);     // 512x768  bf16
    short* W_tagT    = (short*)(ws +  8945664);     // 512x768  bf16
    short* A_ctx     = (short*)(ws +  9142272);     // 8192x768  bf16
    short* A_sc      = (short*)(ws + 12288000);     // 24576x768 bf16 (form rows then tag rows)

    hipLaunchKernelGGL(k_front, dim3(5568), dim3(256), 0, stream,
                       W_enc, W_s, W_c, W_char, W_tag,
                       W_encT, W_sT, W_cT, W_charT, W_tagT,
                       xemb, xtokens, A_ctx);
    hipLaunchKernelGGL(k_gemm_ctx, dim3((NN/128)*(DD/128)), dim3(256), 0, stream,
                       A_ctx, W_encT, b_enc, token_ctx);
    hipLaunchKernelGGL(k_segsum, dim3(TT), dim3(256), 0, stream,
                       tokens, token_ctx, char_emb, tS_bf, cS_bf);
    hipLaunchKernelGGL(k_state_gemm, dim3((TT/128)*(DD/128)), dim3(256), 0, stream,
                       tS_bf, cS_bf, W_sT, W_cT, state);
    hipLaunchKernelGGL(k_prep_scores, dim3((TT*(FF+LL)) * DD / 2048), dim3(256), 0, stream,
                       state, form_pos, tag_pos, char_emb, tag_emb, tfc, ttg, A_sc);
    hipLaunchKernelGGL(k_gemm_scores, dim3((TT*(FF+LL)/128)*(CVV/128)), dim3(256), 0, stream,
                       A_sc, W_charT, W_tagT, out);
}